// Round 12
// baseline (1260.217 us; speedup 1.0000x reference)
//
#include <hip/hip_runtime.h>

#define M 256     // rows of S (n_hos*n_types)
#define N 4096    // cols of S (n_structs)
#define NIT 200   // PDHG iterations
#define PIT 30    // power iterations

// z_s dummy: float2 slot N (byte 32768, kept zero)
#define ZDUMMY (4096*8)

// ---------------- counts ----------------
__global__ void k_colcnt(const float* __restrict__ S, int* __restrict__ col_cnt){
  int j = blockIdx.x*256 + threadIdx.x;
  int c = 0;
  for (int i = 0; i < M; ++i) c += (S[i*N + j] != 0.0f) ? 1 : 0;
  col_cnt[j] = c;
}

// row bitmasks (transposed layout rowmaskT[jc][row]) + row counts
__global__ void k_rowmask(const float* __restrict__ S,
                          unsigned long long* __restrict__ rowmaskT,
                          int* __restrict__ row_cnt){
  int wid = blockIdx.x*(blockDim.x>>6) + (threadIdx.x>>6);
  int l = threadIdx.x & 63;
  if (wid >= M) return;
  int cnt = 0;
  for (int jc = 0; jc < N/64; ++jc){
    float v = S[wid*N + jc*64 + l];
    unsigned long long mask = __ballot(v != 0.0f);
    if (l == 0) rowmaskT[jc*M + wid] = mask;
    cnt += __popcll(mask);
  }
  if (l == 0) row_cnt[wid] = cnt;
}

// ---------------- deterministic rank sort by (cnt, index) ----------------
__global__ void k_sortcol(const int* __restrict__ col_cnt,
                          int* __restrict__ col_perm, int* __restrict__ col_rank){
  __shared__ int cs[N];
  int t0 = threadIdx.x;
  for (int t = 0; t < N/256; ++t) cs[t0 + 256*t] = col_cnt[t0 + 256*t];
  __syncthreads();
  int j = blockIdx.x*256 + t0;
  int cj = cs[j];
  int rank = 0;
  #pragma unroll 4
  for (int jj = 0; jj < N; ++jj){
    int c = cs[jj];
    rank += ((c < cj) || (c == cj && jj < j)) ? 1 : 0;
  }
  col_perm[rank] = j;
  col_rank[j] = rank;
}

__global__ void k_sortrow(const int* __restrict__ row_cnt,
                          int* __restrict__ row_perm, int* __restrict__ row_rank){
  int i = threadIdx.x;
  int ci = row_cnt[i];
  int rank = 0;
  for (int ii = 0; ii < M; ++ii){
    int c = row_cnt[ii];
    rank += ((c < ci) || (c == ci && ii < i)) ? 1 : 0;
  }
  row_perm[rank] = i;
  row_rank[i] = rank;
}

// ---------------- wave-trip counts + base offsets (TRIP units) ----------
__global__ void k_trips(const int* __restrict__ col_cnt, const int* __restrict__ col_perm,
                        const int* __restrict__ row_cnt, const int* __restrict__ row_perm,
                        int* __restrict__ pT4, int* __restrict__ pB4,
                        int* __restrict__ dT4, int* __restrict__ dB4){
  int tid = threadIdx.x;
  if (tid < 64){
    int k = tid >> 4, w = tid & 15;
    int mx = 0;
    for (int l = 0; l < 64; ++l){
      int s = 64*w + l + 1024*k;
      int c = col_cnt[col_perm[s]];
      mx = max(mx, c);
    }
    pT4[tid] = min((mx + 3) >> 2, 16);
  } else if (tid < 80){
    int w = tid - 64;
    int mx = 0;
    for (int l = 0; l < 64; ++l){
      int t = w*64 + l;
      int r = t >> 2, q = t & 3;
      int len = row_cnt[row_perm[r]];
      int qs = (len*q) >> 2, qe = (len*(q+1)) >> 2;
      mx = max(mx, qe - qs);
    }
    dT4[w] = min((mx + 3) >> 2, 80);
  }
  __syncthreads();
  if (tid == 0){
    int acc = 0;
    for (int i = 0; i < 64; ++i){ pB4[i] = acc; acc += pT4[i]; }
    acc = 0;
    for (int i = 0; i < 16; ++i){ dB4[i] = acc; acc += dT4[i]; }
  }
}

// ---------------- primal stream fill: bank-aligned y_rep offsets --------
// y_rep[16][257] float2; item (row i, lane l) -> replica r = (l-i)&15,
// slot = 257r + i; class = slot mod 16 = l mod 16 -> conflict-free b64.
// Dummy = replica (l&15)'s pad slot 257*(l&15)+256 (class-matched, zero).
__global__ void k_fillp(const float* __restrict__ S, const int* __restrict__ col_rank,
                        const int* __restrict__ pT4, const int* __restrict__ pB4,
                        unsigned short* __restrict__ pstream){
  int j = blockIdx.x*256 + threadIdx.x;
  int s = col_rank[j];
  int k = s >> 10, rem = s & 1023, w = rem >> 6, l = rem & 63;
  int kw = k*16 + w;
  int base = pB4[kw];
  int cap = pT4[kw]*4;
  int t = 0;
  for (int i = 0; i < M && t < cap; ++i){
    if (S[i*N + j] != 0.0f){
      int r = (l - i) & 15;
      int slot = r*257 + i;
      pstream[((base + (t>>2))*64 + l)*4 + (t&3)] = (unsigned short)(slot*8);
      ++t;
    }
  }
  const unsigned short dpad = (unsigned short)(((l & 15)*257 + 256)*8);
  for (; t < cap; ++t)
    pstream[((base + (t>>2))*64 + l)*4 + (t&3)] = dpad;
}

// ---------------- dual stream fill: wave per row, ballot scan -----------
__global__ void k_filld(const float* __restrict__ S,
                        const int* __restrict__ row_cnt, const int* __restrict__ row_perm,
                        const int* __restrict__ dT4, const int* __restrict__ dB4,
                        unsigned short* __restrict__ dstream){
  int rr = blockIdx.x;                 // sorted row slot 0..255
  int lf = threadIdx.x;                // 0..63
  int i  = row_perm[rr];
  int len = row_cnt[i];
  int w = rr >> 4;                     // consumer wave
  int base = dB4[w];
  int cap  = dT4[w]*4;
  int qs1 = (len*1) >> 2, qs2 = (len*2) >> 2, qs3 = (len*3) >> 2;
  int lc0 = (rr & 15) << 2;            // consumer lane base

  int pos = 0;
  for (int jc = 0; jc < N/64; ++jc){
    int j = jc*64 + lf;
    float v = S[i*N + j];
    unsigned long long mask = __ballot(v != 0.0f);
    if (v != 0.0f){
      int rank = pos + __popcll(mask & ((1ull << lf) - 1ull));
      int q = (rank >= qs1) + (rank >= qs2) + (rank >= qs3);
      int qs = (q==0) ? 0 : ((q==1) ? qs1 : ((q==2) ? qs2 : qs3));
      int t = rank - qs;
      if (t < cap)
        dstream[((base + (t>>2))*64 + (lc0 + q))*4 + (t&3)] = (unsigned short)(j*8);
    }
    pos += __popcll(mask);
  }
  if (lf < 4){
    int q = lf;
    int qs = (q==0) ? 0 : ((q==1) ? qs1 : ((q==2) ? qs2 : qs3));
    int qe = (q==3) ? len : ((q==0) ? qs1 : ((q==1) ? qs2 : qs3));
    int qlen = qe - qs; if (qlen > cap) qlen = cap;
    for (int t = qlen; t < cap; ++t)
      dstream[((base + (t>>2))*64 + (lc0 + q))*4 + (t&3)] = (unsigned short)ZDUMMY;
  }
}

// ---------------- Gram matrix G = S S^T (exact, u16) --------------------
__global__ __launch_bounds__(256) void k_gram(
    const unsigned long long* __restrict__ rowmaskT,
    unsigned short* __restrict__ G)
{
  __shared__ unsigned long long mi[64];
  const int i = blockIdx.x, t = threadIdx.x;
  if (t < 64) mi[t] = rowmaskT[t*M + i];
  __syncthreads();
  int acc = 0;
  #pragma unroll 8
  for (int w = 0; w < 64; ++w)
    acc += (int)__popcll(mi[w] & rowmaskT[w*M + t]);
  G[i*M + t] = (unsigned short)acc;
}

// ---------------- power iteration on G (dense, 256-dim) -----------------
__global__ __launch_bounds__(1024) void k_powerG(
    const unsigned short* __restrict__ G, const int* __restrict__ row_cnt,
    float* __restrict__ tauw)
{
  __shared__ unsigned short Gs[M*M];     // 128 KB
  __shared__ float uA[M], uB[M];
  __shared__ float part[1024];
  const int t = threadIdx.x;
  const int r = t & 255, q = t >> 8;

  {
    const unsigned* g32 = (const unsigned*)G;
    unsigned* s32 = (unsigned*)Gs;
    for (int k = 0; k < (M*M/2)/1024; ++k) s32[t + 1024*k] = g32[t + 1024*k];
  }
  if (t < M){ uA[t] = (float)row_cnt[t]; }
  __syncthreads();

  for (int it = 0; it < PIT; ++it){
    const float* src = (it & 1) ? uB : uA;
    float* dst = (it & 1) ? uA : uB;
    float acc = 0.0f;
    #pragma unroll 8
    for (int c = 0; c < 64; ++c){
      int cc = q*64 + c;
      acc += (float)Gs[cc*M + r] * src[cc];
    }
    part[t] = acc;
    __syncthreads();
    if (t < M)
      dst[r] = (part[r] + part[r+256] + part[r+512] + part[r+768]) * (1.0f/1024.0f);
    __syncthreads();
  }
  // uA = u30 (c), uB = u29 (a)
  float cc_ = 0.0f, ac_ = 0.0f;
  if (t < M){ cc_ = uA[t]*uA[t]; ac_ = uB[t]*uA[t]; }
  part[t] = cc_;
  __syncthreads();
  for (int sd = 512; sd > 0; sd >>= 1){
    if (t < sd) part[t] += part[t+sd];
    __syncthreads();
  }
  float ccs = part[0];
  __syncthreads();
  part[t] = ac_;
  __syncthreads();
  for (int sd = 512; sd > 0; sd >>= 1){
    if (t < sd) part[t] += part[t+sd];
    __syncthreads();
  }
  if (t == 0){
    float acs = part[0];
    tauw[0] = 0.9f * sqrtf(acs / ccs) * (1.0f/32.0f);
  }
}

// ---------------- persistent PDHG: one block per 2 batches --------------
// y stored 16x-replicated (float2[16][257]) so primal gathers are
// bank-aligned (class = lane mod 16) -> zero conflicts.
__global__ __launch_bounds__(1024) void k_main(
    const float* __restrict__ X,
    const ushort4* __restrict__ pstream, const ushort4* __restrict__ dstream,
    const int* __restrict__ col_perm, const int* __restrict__ row_perm,
    const int* __restrict__ pT4, const int* __restrict__ pB4,
    const int* __restrict__ dT4, const int* __restrict__ dB4,
    const float* __restrict__ tauw, float* __restrict__ out)
{
  __shared__ float2 z_s[N+8];          // 32.8 KB (+dummy at N)
  __shared__ float2 y_rep[16*257];     // 32.9 KB, replica r slot 257r+i
  const int tid = threadIdx.x, w = tid >> 6, l = tid & 63;
  const int b0 = blockIdx.x * 2;
  const float tau = tauw[0];
  const float sigma = tau;

  int cj[4], pb[4], pt[4];
  float2 x[4];
  #pragma unroll
  for (int k = 0; k < 4; ++k){
    int kw = k*16 + w;
    pb[k] = pB4[kw]; pt[k] = pT4[kw];
    cj[k] = col_perm[tid + 1024*k];
    x[k] = make_float2(0.0f, 0.0f);
  }
  const int r = tid >> 2, q = tid & 3;
  const int rid = row_perm[r];
  const int db = dB4[w], dt = dT4[w];
  float2 bi, yv = make_float2(0.0f, 0.0f);
  bi.x = X[b0*M + rid];                // all 4 q-lanes hold the row rhs
  bi.y = X[(b0+1)*M + rid];
  for (int t = tid; t < 16*257; t += 1024) y_rep[t] = make_float2(0.0f, 0.0f);
  if (tid < 8) z_s[N+tid] = make_float2(0.0f, 0.0f);
  __syncthreads();

  const char* yb = (const char*)y_rep;
  const char* zb = (const char*)z_s;

  for (int it = 0; it < NIT; ++it){
    const bool last = (it == NIT-1);
    // primal: x+ = max(x + tau*(1 - y S), 0); z = 2 x+ - x
    #pragma unroll
    for (int k = 0; k < 4; ++k){
      float ax = 0.0f, ay = 0.0f;
      for (int c = 0; c < pt[k]; ++c){
        ushort4 ix = pstream[(pb[k] + c)*64 + l];
        float2 a0 = *(const float2*)(yb + ix.x);
        float2 a1 = *(const float2*)(yb + ix.y);
        float2 a2 = *(const float2*)(yb + ix.z);
        float2 a3 = *(const float2*)(yb + ix.w);
        ax += (a0.x + a1.x) + (a2.x + a3.x);
        ay += (a0.y + a1.y) + (a2.y + a3.y);
      }
      float2 xo = x[k];
      float xnx = fmaxf(xo.x + tau*(1.0f - ax), 0.0f);
      float xny = fmaxf(xo.y + tau*(1.0f - ay), 0.0f);
      if (!last) z_s[cj[k]] = make_float2(2.0f*xnx - xo.x, 2.0f*xny - xo.y);
      x[k] = make_float2(xnx, xny);
    }
    if (last) break;
    __syncthreads();
    // dual: quarter-row gathers + in-wave reduce across q
    float ax = 0.0f, ay = 0.0f;
    for (int c = 0; c < dt; ++c){
      ushort4 ix = dstream[(db + c)*64 + l];
      float2 a0 = *(const float2*)(zb + ix.x);
      float2 a1 = *(const float2*)(zb + ix.y);
      float2 a2 = *(const float2*)(zb + ix.z);
      float2 a3 = *(const float2*)(zb + ix.w);
      ax += (a0.x + a1.x) + (a2.x + a3.x);
      ay += (a0.y + a1.y) + (a2.y + a3.y);
    }
    ax += __shfl_xor(ax, 1);  ay += __shfl_xor(ay, 1);
    ax += __shfl_xor(ax, 2);  ay += __shfl_xor(ay, 2);
    // all 4 q-lanes hold identical sums (commutative adds) -> each writes
    // 4 replicas; banks (rid+4q+k) mod 16 are exactly 4-per-class (floor)
    yv.x = fmaxf(yv.x + sigma*(ax - bi.x), 0.0f);
    yv.y = fmaxf(yv.y + sigma*(ay - bi.y), 0.0f);
    #pragma unroll
    for (int k2 = 0; k2 < 4; ++k2)
      y_rep[(q*4 + k2)*257 + rid] = yv;
    __syncthreads();
  }

  #pragma unroll
  for (int k = 0; k < 4; ++k){
    out[(size_t)b0*N + cj[k]]     = x[k].x;
    out[(size_t)(b0+1)*N + cj[k]] = x[k].y;
  }
}

// ---------------- launcher ----------------
extern "C" void kernel_launch(void* const* d_in, const int* in_sizes, int n_in,
                              void* d_out, int out_size, void* d_ws, size_t ws_size,
                              hipStream_t stream)
{
  const float* X = (const float*)d_in[0];   // [B, 16, 16] -> b
  const float* S = (const float*)d_in[1];   // [M, N]
  float* out = (float*)d_out;               // [B, N] fp32
  const int B = in_sizes[0] / M;            // 512

  char* p = (char*)d_ws;
  auto alloc = [&](size_t bytes)->char*{
    char* q = p; p += (bytes + 255) & ~size_t(255); return q;
  };
  int* col_cnt  = (int*)alloc(N*sizeof(int));
  int* col_perm = (int*)alloc(N*sizeof(int));
  int* col_rank = (int*)alloc(N*sizeof(int));
  int* row_cnt  = (int*)alloc(M*sizeof(int));
  int* row_perm = (int*)alloc(M*sizeof(int));
  int* row_rank = (int*)alloc(M*sizeof(int));
  int* pT4      = (int*)alloc(64*sizeof(int));
  int* pB4      = (int*)alloc(64*sizeof(int));
  int* dT4      = (int*)alloc(16*sizeof(int));
  int* dB4      = (int*)alloc(16*sizeof(int));
  float* tauw   = (float*)alloc(256);
  unsigned long long* rowmaskT = (unsigned long long*)alloc((N/64)*M*sizeof(unsigned long long));
  unsigned short* G       = (unsigned short*)alloc((size_t)M*M*sizeof(unsigned short));
  unsigned short* pstream = (unsigned short*)alloc(65536ull*8);
  unsigned short* dstream = (unsigned short*)alloc(81920ull*8);

  k_colcnt <<<N/256, 256, 0, stream>>>(S, col_cnt);
  k_rowmask<<<16, 1024, 0, stream>>>(S, rowmaskT, row_cnt);
  k_sortcol<<<N/256, 256, 0, stream>>>(col_cnt, col_perm, col_rank);
  k_sortrow<<<1, M, 0, stream>>>(row_cnt, row_perm, row_rank);
  k_trips  <<<1, 256, 0, stream>>>(col_cnt, col_perm, row_cnt, row_perm, pT4, pB4, dT4, dB4);
  k_fillp  <<<N/256, 256, 0, stream>>>(S, col_rank, pT4, pB4, pstream);
  k_filld  <<<M, 64, 0, stream>>>(S, row_cnt, row_perm, dT4, dB4, dstream);
  k_gram   <<<M, 256, 0, stream>>>(rowmaskT, G);
  k_powerG <<<1, 1024, 0, stream>>>(G, row_cnt, tauw);
  k_main   <<<B/2, 1024, 0, stream>>>(X, (const ushort4*)pstream, (const ushort4*)dstream,
                                      col_perm, row_perm, pT4, pB4, dT4, dB4, tauw, out);
}

// Round 13
// 1227.925 us; speedup vs baseline: 1.0263x; 1.0263x over previous
//
#include <hip/hip_runtime.h>

#define M 256     // rows of S (n_hos*n_types)
#define N 4096    // cols of S (n_structs)
#define NIT 200   // PDHG iterations
#define PIT 30    // power iterations

// dummy byte-offsets (float2 slots): y_s[256], z_s[4096]
#define YDUMMY (256*8)
#define ZDUMMY (4096*8)

// ---------------- counts ----------------
__global__ void k_colcnt(const float* __restrict__ S, int* __restrict__ col_cnt){
  int j = blockIdx.x*256 + threadIdx.x;
  int c = 0;
  for (int i = 0; i < M; ++i) c += (S[i*N + j] != 0.0f) ? 1 : 0;
  col_cnt[j] = c;
}

// row bitmasks (transposed layout rowmaskT[jc][row]) + row counts
__global__ void k_rowmask(const float* __restrict__ S,
                          unsigned long long* __restrict__ rowmaskT,
                          int* __restrict__ row_cnt){
  int wid = blockIdx.x*(blockDim.x>>6) + (threadIdx.x>>6);
  int l = threadIdx.x & 63;
  if (wid >= M) return;
  int cnt = 0;
  for (int jc = 0; jc < N/64; ++jc){
    float v = S[wid*N + jc*64 + l];
    unsigned long long mask = __ballot(v != 0.0f);
    if (l == 0) rowmaskT[jc*M + wid] = mask;
    cnt += __popcll(mask);
  }
  if (l == 0) row_cnt[wid] = cnt;
}

// ---------------- deterministic rank sort by (cnt, index) ----------------
__global__ void k_sortcol(const int* __restrict__ col_cnt,
                          int* __restrict__ col_perm, int* __restrict__ col_rank){
  __shared__ int cs[N];
  int t0 = threadIdx.x;
  for (int t = 0; t < N/256; ++t) cs[t0 + 256*t] = col_cnt[t0 + 256*t];
  __syncthreads();
  int j = blockIdx.x*256 + t0;
  int cj = cs[j];
  int rank = 0;
  #pragma unroll 4
  for (int jj = 0; jj < N; ++jj){
    int c = cs[jj];
    rank += ((c < cj) || (c == cj && jj < j)) ? 1 : 0;
  }
  col_perm[rank] = j;
  col_rank[j] = rank;
}

// ---------------- fused: row sort + trips + prefix (one block) ----------
__global__ __launch_bounds__(256) void k_rowsetup(
    const int* __restrict__ row_cnt, const int* __restrict__ col_cnt,
    const int* __restrict__ col_perm,
    int* __restrict__ row_perm,
    int* __restrict__ pT4, int* __restrict__ pB4,
    int* __restrict__ dT4, int* __restrict__ dB4)
{
  __shared__ int rp[M];
  int tid = threadIdx.x;
  // row rank sort
  {
    int i = tid;
    int ci = row_cnt[i];
    int rank = 0;
    for (int ii = 0; ii < M; ++ii){
      int c = row_cnt[ii];
      rank += ((c < ci) || (c == ci && ii < i)) ? 1 : 0;
    }
    rp[rank] = i;
  }
  __syncthreads();
  if (tid < M) row_perm[tid] = rp[tid];
  // trips
  if (tid < 64){
    int k = tid >> 4, w = tid & 15;
    int mx = 0;
    for (int l = 0; l < 64; ++l){
      int s = 64*w + l + 1024*k;
      int c = col_cnt[col_perm[s]];
      mx = max(mx, c);
    }
    pT4[tid] = min((mx + 3) >> 2, 16);
  } else if (tid < 80){
    int w = tid - 64;
    int mx = 0;
    for (int l = 0; l < 64; ++l){
      int t = w*64 + l;
      int r = t >> 2, q = t & 3;
      int len = row_cnt[rp[r]];
      int qs = (len*q) >> 2, qe = (len*(q+1)) >> 2;
      mx = max(mx, qe - qs);
    }
    dT4[w] = min((mx + 3) >> 2, 80);
  }
  __syncthreads();
  if (tid == 0){
    int acc = 0;
    for (int i = 0; i < 64; ++i){ pB4[i] = acc; acc += pT4[i]; }
    acc = 0;
    for (int i = 0; i < 16; ++i){ dB4[i] = acc; acc += dT4[i]; }
  }
}

// ---------------- primal stream fill (transposed, padded) ----------------
__global__ void k_fillp(const float* __restrict__ S, const int* __restrict__ col_rank,
                        const int* __restrict__ pT4, const int* __restrict__ pB4,
                        unsigned short* __restrict__ pstream){
  int j = blockIdx.x*256 + threadIdx.x;
  int s = col_rank[j];
  int k = s >> 10, rem = s & 1023, w = rem >> 6, l = rem & 63;
  int kw = k*16 + w;
  int base = pB4[kw];
  int cap = pT4[kw]*4;
  int t = 0;
  for (int i = 0; i < M && t < cap; ++i){
    if (S[i*N + j] != 0.0f){
      pstream[((base + (t>>2))*64 + l)*4 + (t&3)] = (unsigned short)(i*8);
      ++t;
    }
  }
  for (; t < cap; ++t)
    pstream[((base + (t>>2))*64 + l)*4 + (t&3)] = (unsigned short)YDUMMY;
}

// ---------------- dual stream fill: wave per row, ballot scan -----------
__global__ void k_filld(const float* __restrict__ S,
                        const int* __restrict__ row_cnt, const int* __restrict__ row_perm,
                        const int* __restrict__ dT4, const int* __restrict__ dB4,
                        unsigned short* __restrict__ dstream){
  int rr = blockIdx.x;                 // sorted row slot 0..255
  int lf = threadIdx.x;                // 0..63
  int i  = row_perm[rr];
  int len = row_cnt[i];
  int w = rr >> 4;                     // consumer wave
  int base = dB4[w];
  int cap  = dT4[w]*4;
  int qs1 = (len*1) >> 2, qs2 = (len*2) >> 2, qs3 = (len*3) >> 2;
  int lc0 = (rr & 15) << 2;            // consumer lane base

  int pos = 0;
  for (int jc = 0; jc < N/64; ++jc){
    int j = jc*64 + lf;
    float v = S[i*N + j];
    unsigned long long mask = __ballot(v != 0.0f);
    if (v != 0.0f){
      int rank = pos + __popcll(mask & ((1ull << lf) - 1ull));
      int q = (rank >= qs1) + (rank >= qs2) + (rank >= qs3);
      int qs = (q==0) ? 0 : ((q==1) ? qs1 : ((q==2) ? qs2 : qs3));
      int t = rank - qs;
      if (t < cap)
        dstream[((base + (t>>2))*64 + (lc0 + q))*4 + (t&3)] = (unsigned short)(j*8);
    }
    pos += __popcll(mask);
  }
  if (lf < 4){
    int q = lf;
    int qs = (q==0) ? 0 : ((q==1) ? qs1 : ((q==2) ? qs2 : qs3));
    int qe = (q==3) ? len : ((q==0) ? qs1 : ((q==1) ? qs2 : qs3));
    int qlen = qe - qs; if (qlen > cap) qlen = cap;
    for (int t = qlen; t < cap; ++t)
      dstream[((base + (t>>2))*64 + (lc0 + q))*4 + (t&3)] = (unsigned short)ZDUMMY;
  }
}

// ---------------- Gram matrix G = S S^T (exact, u16) --------------------
__global__ __launch_bounds__(256) void k_gram(
    const unsigned long long* __restrict__ rowmaskT,
    unsigned short* __restrict__ G)
{
  __shared__ unsigned long long mi[64];
  const int i = blockIdx.x, t = threadIdx.x;
  if (t < 64) mi[t] = rowmaskT[t*M + i];
  __syncthreads();
  int acc = 0;
  #pragma unroll 8
  for (int w = 0; w < 64; ++w)
    acc += (int)__popcll(mi[w] & rowmaskT[w*M + t]);
  G[i*M + t] = (unsigned short)acc;
}

// ---------------- power iteration on G (dense, 256-dim) -----------------
__global__ __launch_bounds__(1024) void k_powerG(
    const unsigned short* __restrict__ G, const int* __restrict__ row_cnt,
    float* __restrict__ tauw)
{
  __shared__ unsigned short Gs[M*M];     // 128 KB
  __shared__ float uA[M], uB[M];
  __shared__ float part[1024];
  const int t = threadIdx.x;
  const int r = t & 255, q = t >> 8;

  {
    const unsigned* g32 = (const unsigned*)G;
    unsigned* s32 = (unsigned*)Gs;
    for (int k = 0; k < (M*M/2)/1024; ++k) s32[t + 1024*k] = g32[t + 1024*k];
  }
  if (t < M){ uA[t] = (float)row_cnt[t]; }
  __syncthreads();

  for (int it = 0; it < PIT; ++it){
    const float* src = (it & 1) ? uB : uA;
    float* dst = (it & 1) ? uA : uB;
    float acc = 0.0f;
    #pragma unroll 8
    for (int c = 0; c < 64; ++c){
      int cc = q*64 + c;
      acc += (float)Gs[cc*M + r] * src[cc];
    }
    part[t] = acc;
    __syncthreads();
    if (t < M)
      dst[r] = (part[r] + part[r+256] + part[r+512] + part[r+768]) * (1.0f/1024.0f);
    __syncthreads();
  }
  // uA = u30 (c), uB = u29 (a)
  float cc_ = 0.0f, ac_ = 0.0f;
  if (t < M){ cc_ = uA[t]*uA[t]; ac_ = uB[t]*uA[t]; }
  part[t] = cc_;
  __syncthreads();
  for (int sd = 512; sd > 0; sd >>= 1){
    if (t < sd) part[t] += part[t+sd];
    __syncthreads();
  }
  float ccs = part[0];
  __syncthreads();
  part[t] = ac_;
  __syncthreads();
  for (int sd = 512; sd > 0; sd >>= 1){
    if (t < sd) part[t] += part[t+sd];
    __syncthreads();
  }
  if (t == 0){
    float acs = part[0];
    tauw[0] = 0.9f * sqrtf(acs / ccs) * (1.0f/32.0f);
  }
}

// ---------------- persistent PDHG: one block per 2 batches --------------
__global__ __launch_bounds__(1024) void k_main(
    const float* __restrict__ X,
    const ushort4* __restrict__ pstream, const ushort4* __restrict__ dstream,
    const int* __restrict__ col_perm, const int* __restrict__ row_perm,
    const int* __restrict__ pT4, const int* __restrict__ pB4,
    const int* __restrict__ dT4, const int* __restrict__ dB4,
    const float* __restrict__ tauw, float* __restrict__ out)
{
  __shared__ float2 z_s[N+8];
  __shared__ float2 y_s[M+8];
  const int tid = threadIdx.x, w = tid >> 6, l = tid & 63;
  const int b0 = blockIdx.x * 2;
  const float tau = tauw[0];
  const float sigma = tau;

  int cj[4], pb[4], pt[4];
  float2 x[4];
  #pragma unroll
  for (int k = 0; k < 4; ++k){
    int kw = k*16 + w;
    pb[k] = pB4[kw]; pt[k] = pT4[kw];
    cj[k] = col_perm[tid + 1024*k];
    x[k] = make_float2(0.0f, 0.0f);
  }
  const int r = tid >> 2, q = tid & 3;
  const int rid = row_perm[r];
  const int db = dB4[w], dt = dT4[w];
  float2 bi = make_float2(0,0), yv = make_float2(0,0);
  if (q == 0){
    bi.x = X[b0*M + rid];
    bi.y = X[(b0+1)*M + rid];
    y_s[rid] = make_float2(0,0);
  }
  if (tid < 8){ y_s[M+tid] = make_float2(0,0); z_s[N+tid] = make_float2(0,0); }
  __syncthreads();

  const char* yb = (const char*)y_s;
  const char* zb = (const char*)z_s;

  for (int it = 0; it < NIT; ++it){
    const bool last = (it == NIT-1);
    // primal: x+ = max(x + tau*(1 - y S), 0); z = 2 x+ - x
    #pragma unroll
    for (int k = 0; k < 4; ++k){
      float ax = 0.0f, ay = 0.0f;
      for (int c = 0; c < pt[k]; ++c){
        ushort4 ix = pstream[(pb[k] + c)*64 + l];
        float2 a0 = *(const float2*)(yb + ix.x);
        float2 a1 = *(const float2*)(yb + ix.y);
        float2 a2 = *(const float2*)(yb + ix.z);
        float2 a3 = *(const float2*)(yb + ix.w);
        ax += (a0.x + a1.x) + (a2.x + a3.x);
        ay += (a0.y + a1.y) + (a2.y + a3.y);
      }
      float2 xo = x[k];
      float xnx = fmaxf(xo.x + tau*(1.0f - ax), 0.0f);
      float xny = fmaxf(xo.y + tau*(1.0f - ay), 0.0f);
      if (!last) z_s[cj[k]] = make_float2(2.0f*xnx - xo.x, 2.0f*xny - xo.y);
      x[k] = make_float2(xnx, xny);
    }
    if (last) break;
    __syncthreads();
    // dual: quarter-row gathers + in-wave reduce across q
    float ax = 0.0f, ay = 0.0f;
    for (int c = 0; c < dt; ++c){
      ushort4 ix = dstream[(db + c)*64 + l];
      float2 a0 = *(const float2*)(zb + ix.x);
      float2 a1 = *(const float2*)(zb + ix.y);
      float2 a2 = *(const float2*)(zb + ix.z);
      float2 a3 = *(const float2*)(zb + ix.w);
      ax += (a0.x + a1.x) + (a2.x + a3.x);
      ay += (a0.y + a1.y) + (a2.y + a3.y);
    }
    ax += __shfl_xor(ax, 1);  ay += __shfl_xor(ay, 1);
    ax += __shfl_xor(ax, 2);  ay += __shfl_xor(ay, 2);
    if (q == 0){
      yv.x = fmaxf(yv.x + sigma*(ax - bi.x), 0.0f);
      yv.y = fmaxf(yv.y + sigma*(ay - bi.y), 0.0f);
      y_s[rid] = yv;
    }
    __syncthreads();
  }

  #pragma unroll
  for (int k = 0; k < 4; ++k){
    out[(size_t)b0*N + cj[k]]     = x[k].x;
    out[(size_t)(b0+1)*N + cj[k]] = x[k].y;
  }
}

// ---------------- launcher ----------------
extern "C" void kernel_launch(void* const* d_in, const int* in_sizes, int n_in,
                              void* d_out, int out_size, void* d_ws, size_t ws_size,
                              hipStream_t stream)
{
  const float* X = (const float*)d_in[0];   // [B, 16, 16] -> b
  const float* S = (const float*)d_in[1];   // [M, N]
  float* out = (float*)d_out;               // [B, N] fp32
  const int B = in_sizes[0] / M;            // 512

  char* p = (char*)d_ws;
  auto alloc = [&](size_t bytes)->char*{
    char* q = p; p += (bytes + 255) & ~size_t(255); return q;
  };
  int* col_cnt  = (int*)alloc(N*sizeof(int));
  int* col_perm = (int*)alloc(N*sizeof(int));
  int* col_rank = (int*)alloc(N*sizeof(int));
  int* row_cnt  = (int*)alloc(M*sizeof(int));
  int* row_perm = (int*)alloc(M*sizeof(int));
  int* pT4      = (int*)alloc(64*sizeof(int));
  int* pB4      = (int*)alloc(64*sizeof(int));
  int* dT4      = (int*)alloc(16*sizeof(int));
  int* dB4      = (int*)alloc(16*sizeof(int));
  float* tauw   = (float*)alloc(256);
  unsigned long long* rowmaskT = (unsigned long long*)alloc((N/64)*M*sizeof(unsigned long long));
  unsigned short* G       = (unsigned short*)alloc((size_t)M*M*sizeof(unsigned short));
  unsigned short* pstream = (unsigned short*)alloc(65536ull*8);
  unsigned short* dstream = (unsigned short*)alloc(81920ull*8);

  k_colcnt  <<<N/256, 256, 0, stream>>>(S, col_cnt);
  k_rowmask <<<16, 1024, 0, stream>>>(S, rowmaskT, row_cnt);
  k_sortcol <<<N/256, 256, 0, stream>>>(col_cnt, col_perm, col_rank);
  k_rowsetup<<<1, 256, 0, stream>>>(row_cnt, col_cnt, col_perm, row_perm,
                                    pT4, pB4, dT4, dB4);
  k_fillp   <<<N/256, 256, 0, stream>>>(S, col_rank, pT4, pB4, pstream);
  k_filld   <<<M, 64, 0, stream>>>(S, row_cnt, row_perm, dT4, dB4, dstream);
  k_gram    <<<M, 256, 0, stream>>>(rowmaskT, G);
  k_powerG  <<<1, 1024, 0, stream>>>(G, row_cnt, tauw);
  k_main    <<<B/2, 1024, 0, stream>>>(X, (const ushort4*)pstream, (const ushort4*)dstream,
                                       col_perm, row_perm, pT4, pB4, dT4, dB4, tauw, out);
}